// Round 6
// baseline (467.990 us; speedup 1.0000x reference)
//
#include <hip/hip_runtime.h>
#include <hip/hip_bf16.h>
#include <hip/hip_cooperative_groups.h>

namespace cg = cooperative_groups;

#define LL 2048
#define DM 512
// (1/sqrt(2048)) * log2(e): softmax exp(x) computed as exp2(x'); fold into Q pre-scale
#define SCALE2 0.031879357f

typedef unsigned short u16;
typedef __attribute__((ext_vector_type(8))) short short8;    // 8 bf16 (4 VGPRs)
typedef __attribute__((ext_vector_type(4))) short short4v;   // 4 bf16 (2 VGPRs)
typedef __attribute__((ext_vector_type(4))) float f32x4;     // MFMA C/D

// ws layout (u16 element offsets), ~27 MB of the 256 MiB ws:
//  XAQ/XAK/XAV: bf16 inputs in proj-A-frag order [2][128 r16][16 kt][64 lane][8]
//  WB : bf16 weights in B-frag order [3][8][16 kt][4 nt][64 lane][8]
//  QA/KA: bf16 Q,K projections in frag order (Q pre-scaled by SCALE2)
//  VB : bf16 V in PAIRED PV-B-frag order [16 kt2][4 w][4 et][64 lane][8]
//       (j<4 = keys of kt=2*kt2, j>=4 = keys of kt=2*kt2+1) for K=32 PV MFMA
//  S  : f32 Sinv [16][2048]
#define XAQ_OFF 0u
#define XAK_OFF 2097152u
#define XAV_OFF 4194304u
#define WB_OFF  6291456u
#define QA_OFF  7077888u
#define KA_OFF  9175040u
#define VB_OFF  11272192u
#define S_OFF   13369344u    // float region, 32768 floats

__device__ __forceinline__ u16 f2bf(float f) {
  union { float f; unsigned u; } v; v.f = f;
  unsigned r = v.u + 0x7fff + ((v.u >> 16) & 1);   // RNE
  return (u16)(r >> 16);
}
__device__ __forceinline__ size_t frag_idx(int bh, int t64, int w, int c, int lane) {
  return ((((size_t)(bh * 32 + t64) * 4 + w) * 2 + c) * 64 + lane) * 8;
}
// paired VB layout for K=32 PV: 16B word per (kt2,w,et,lane)
__device__ __forceinline__ size_t vb8_idx(int bh, int kt2, int w, int et, int lane) {
  return ((((size_t)(bh * 16 + kt2) * 4 + w) * 4 + et) * 64 + lane) * 8;
}

// ==================== phase bodies (shared by fused + fallback) ====================

__device__ __forceinline__ void prep_body(
    int vb, int t, u16* Xs /*[16][520]*/,
    const float* __restrict__ queries, const float* __restrict__ keys,
    const float* __restrict__ values, const float* __restrict__ WQ,
    const float* __restrict__ WK, const float* __restrict__ WV,
    u16* __restrict__ wsb) {
  if (vb < 768) {
    int tens = vb >> 8;                        // 0=Q,1=K,2=V
    int grp  = vb & 255;                       // b*128 + r16
    const float* src = (tens == 0 ? queries : tens == 1 ? keys : values) +
                       (size_t)grp * 16 * 512;
#pragma unroll
    for (int rep = 0; rep < 8; ++rep) {
      int f4 = t + rep * 256;                  // 0..2047
      int row = f4 >> 7, c4 = f4 & 127;
      float4 v = *(const float4*)(src + (size_t)row * 512 + c4 * 4);
      short4v o;
      o[0] = (short)f2bf(v.x); o[1] = (short)f2bf(v.y);
      o[2] = (short)f2bf(v.z); o[3] = (short)f2bf(v.w);
      *(short4v*)&Xs[row * 520 + c4 * 4] = o;
    }
    __syncthreads();
    u16* dst = wsb + (tens == 0 ? XAQ_OFF : tens == 1 ? XAK_OFF : XAV_OFF) +
               (size_t)grp * 16 * 64 * 8;
#pragma unroll
    for (int rep = 0; rep < 4; ++rep) {
      int o = t + rep * 256;                   // kt*64 + lane
      int kt = o >> 6, lane = o & 63;
      int quad = lane >> 4, l16 = lane & 15;
      short8 v = *(const short8*)&Xs[l16 * 520 + kt * 32 + quad * 8];
      *(short8*)(dst + (size_t)o * 8) = v;
    }
    __syncthreads();                           // Xs reused by next grid-stride iter
  } else {
    int c2 = (vb - 768) * 256 + t;             // 0..98303
    int lane = c2 & 63;
    int nt = (c2 >> 6) & 3;
    int kt = (c2 >> 8) & 15;
    int h  = (c2 >> 12) & 7;
    int z  = c2 >> 15;
    int quad = lane >> 4, l16 = lane & 15;
    const float* W = (z == 0) ? WQ : (z == 1) ? WK : WV;
    const float* src = W + ((size_t)h * DM + kt * 32 + quad * 8) * 64 + nt * 16 + l16;
    short8 o;
#pragma unroll
    for (int j = 0; j < 8; ++j) o[j] = (short)f2bf(src[(size_t)j * 64]);
    *(short8*)(wsb + WB_OFF + (size_t)c2 * 8) = o;
  }
}

__device__ __forceinline__ void proj_body(
    int z, int bh, int QT, int t, float* Cs /*[64][68]*/, u16* __restrict__ wsb) {
  int lane = t & 63, w = t >> 6, quad = lane >> 4, l16 = lane & 15;
  int b = bh >> 3, h = bh & 7;

  const u16* Bw = wsb + WB_OFF + ((size_t)(z * 8 + h) * 16) * 4 * 64 * 8;
  const u16* Ab = wsb + (z == 0 ? XAQ_OFF : z == 1 ? XAK_OFF : XAV_OFF) +
      (((size_t)b * 128 + QT * 4 + w) * 16) * 64 * 8;

  f32x4 acc[4];
#pragma unroll
  for (int nt = 0; nt < 4; ++nt) acc[nt] = (f32x4){0.f, 0.f, 0.f, 0.f};

#pragma unroll 4
  for (int kt = 0; kt < 16; ++kt) {
    short8 a = *(const short8*)(Ab + ((size_t)kt * 64 + lane) * 8);
#pragma unroll
    for (int nt = 0; nt < 4; ++nt) {
      short8 bb = *(const short8*)(Bw + (((size_t)kt * 4 + nt) * 64 + lane) * 8);
      acc[nt] = __builtin_amdgcn_mfma_f32_16x16x32_bf16(a, bb, acc[nt], 0, 0, 0);
    }
  }

  float sc = (z == 0) ? SCALE2 : 1.0f;         // exp2-fold: SCALE * log2(e)
#pragma unroll
  for (int nt = 0; nt < 4; ++nt)
#pragma unroll
    for (int r = 0; r < 4; ++r)
      Cs[(w * 16 + quad * 4 + r) * 68 + nt * 16 + l16] = acc[nt][r] * sc;
  __syncthreads();

  if (z < 2) {
    u16* base = wsb + (z == 0 ? QA_OFF : KA_OFF);
#pragma unroll
    for (int c = 0; c < 2; ++c) {
      const float* srcr = &Cs[(w * 16 + l16) * 68 + c * 32 + quad * 8];
      short8 o;
#pragma unroll
      for (int j = 0; j < 8; ++j) o[j] = (short)f2bf(srcr[j]);
      *(short8*)(base + frag_idx(bh, QT, w, c, lane)) = o;
    }
  } else {
    // paired PV-B layout: kt = QT writes the 8-byte half-word (QT&1) at kt2 = QT>>1
#pragma unroll
    for (int et = 0; et < 4; ++et) {
      short4v o;
#pragma unroll
      for (int j = 0; j < 4; ++j)
        o[j] = (short)f2bf(Cs[(w * 16 + quad * 4 + j) * 68 + et * 16 + l16]);
      *(short4v*)(wsb + VB_OFF + vb8_idx(bh, QT >> 1, w, et, lane) + (QT & 1) * 4) = o;
    }
  }
  __syncthreads();                             // Cs reused by next z
}

__device__ __forceinline__ void stats_body(
    int bh, int KT, int t, float* Sred /*[4][64]*/, u16* __restrict__ wsb) {
  int lane = t & 63, w = t >> 6, quad = lane >> 4, l16 = lane & 15;

  short8 ka[4][2];
#pragma unroll
  for (int mt = 0; mt < 4; ++mt)
#pragma unroll
    for (int c = 0; c < 2; ++c)
      ka[mt][c] = *(const short8*)(wsb + KA_OFF + frag_idx(bh, KT, mt, c, lane));

  float rs[4][4];
#pragma unroll
  for (int mt = 0; mt < 4; ++mt)
#pragma unroll
    for (int r = 0; r < 4; ++r) rs[mt][r] = 0.f;

  short8 qb0 = *(const short8*)(wsb + QA_OFF + frag_idx(bh, 0, w, 0, lane));
  short8 qb1 = *(const short8*)(wsb + QA_OFF + frag_idx(bh, 0, w, 1, lane));
  for (int qt = 0; qt < 32; ++qt) {
    int qn = (qt + 1) & 31;
    short8 nq0 = *(const short8*)(wsb + QA_OFF + frag_idx(bh, qn, w, 0, lane));
    short8 nq1 = *(const short8*)(wsb + QA_OFF + frag_idx(bh, qn, w, 1, lane));
#pragma unroll
    for (int mt = 0; mt < 4; ++mt) {
      f32x4 y = (f32x4){0.f, 0.f, 0.f, 0.f};
      __builtin_amdgcn_s_setprio(1);
      y = __builtin_amdgcn_mfma_f32_16x16x32_bf16(ka[mt][0], qb0, y, 0, 0, 0);
      y = __builtin_amdgcn_mfma_f32_16x16x32_bf16(ka[mt][1], qb1, y, 0, 0, 0);
      __builtin_amdgcn_s_setprio(0);
#pragma unroll
      for (int r = 0; r < 4; ++r) rs[mt][r] += __builtin_amdgcn_exp2f(y[r]);
    }
    qb0 = nq0; qb1 = nq1;
  }
#pragma unroll
  for (int mt = 0; mt < 4; ++mt)
#pragma unroll
    for (int r = 0; r < 4; ++r) {
      rs[mt][r] += __shfl_xor(rs[mt][r], 1);
      rs[mt][r] += __shfl_xor(rs[mt][r], 2);
      rs[mt][r] += __shfl_xor(rs[mt][r], 4);
      rs[mt][r] += __shfl_xor(rs[mt][r], 8);
    }

  if (l16 == 0) {
#pragma unroll
    for (int mt = 0; mt < 4; ++mt)
#pragma unroll
      for (int r = 0; r < 4; ++r)
        Sred[w * 64 + mt * 16 + quad * 4 + r] = rs[mt][r];
  }
  __syncthreads();
  if (t < 64) {
    float s = Sred[0 * 64 + t] + Sred[1 * 64 + t] + Sred[2 * 64 + t] + Sred[3 * 64 + t];
    float* S = (float*)(wsb + S_OFF);
    S[(size_t)bh * LL + KT * 64 + t] = 1.0f / s;
  }
  __syncthreads();
}

__device__ __forceinline__ void attn_body(
    int bh, int QT, int t, float* red /*[4][64][68]*/,
    const u16* __restrict__ wsb, float* __restrict__ out) {
  int lane = t & 63, w = t >> 6, quad = lane >> 4, l16 = lane & 15;
  int b = bh >> 3, h = bh & 7;
  int qbase = QT * 64;
  const float* S = (const float*)(wsb + S_OFF) + (size_t)bh * LL;

  short8 qf[4][2];
#pragma unroll
  for (int nt = 0; nt < 4; ++nt)
#pragma unroll
    for (int c = 0; c < 2; ++c)
      qf[nt][c] = *(const short8*)(wsb + QA_OFF + frag_idx(bh, QT, nt, c, lane));

  f32x4 oacc[4][4];
#pragma unroll
  for (int nt = 0; nt < 4; ++nt)
#pragma unroll
    for (int et = 0; et < 4; ++et) oacc[nt][et] = (f32x4){0.f, 0.f, 0.f, 0.f};

  short8 kae0 = *(const short8*)(wsb + KA_OFF + frag_idx(bh, 0, w, 0, lane));
  short8 kae1 = *(const short8*)(wsb + KA_OFF + frag_idx(bh, 0, w, 1, lane));
  short8 kao0 = *(const short8*)(wsb + KA_OFF + frag_idx(bh, 1, w, 0, lane));
  short8 kao1 = *(const short8*)(wsb + KA_OFF + frag_idx(bh, 1, w, 1, lane));
  short8 vb8[4];
#pragma unroll
  for (int et = 0; et < 4; ++et)
    vb8[et] = *(const short8*)(wsb + VB_OFF + vb8_idx(bh, 0, w, et, lane));
  float4 s4e = *(const float4*)(S + 0 * 64 + w * 16 + quad * 4);
  float4 s4o = *(const float4*)(S + 1 * 64 + w * 16 + quad * 4);

  for (int kt2 = 0; kt2 < 16; ++kt2) {
    int kne = (2 * kt2 + 2) & 31, kno = (2 * kt2 + 3) & 31;
    int k2n = (kt2 + 1) & 15;
    short8 nkae0 = *(const short8*)(wsb + KA_OFF + frag_idx(bh, kne, w, 0, lane));
    short8 nkae1 = *(const short8*)(wsb + KA_OFF + frag_idx(bh, kne, w, 1, lane));
    short8 nkao0 = *(const short8*)(wsb + KA_OFF + frag_idx(bh, kno, w, 0, lane));
    short8 nkao1 = *(const short8*)(wsb + KA_OFF + frag_idx(bh, kno, w, 1, lane));
    short8 nvb8[4];
#pragma unroll
    for (int et = 0; et < 4; ++et)
      nvb8[et] = *(const short8*)(wsb + VB_OFF + vb8_idx(bh, k2n, w, et, lane));
    float4 ns4e = *(const float4*)(S + kne * 64 + w * 16 + quad * 4);
    float4 ns4o = *(const float4*)(S + kno * 64 + w * 16 + quad * 4);

#pragma unroll
    for (int nt = 0; nt < 4; ++nt) {
      f32x4 ye = (f32x4){0.f, 0.f, 0.f, 0.f};
      f32x4 yo = (f32x4){0.f, 0.f, 0.f, 0.f};
      __builtin_amdgcn_s_setprio(1);
      ye = __builtin_amdgcn_mfma_f32_16x16x32_bf16(kae0, qf[nt][0], ye, 0, 0, 0);
      ye = __builtin_amdgcn_mfma_f32_16x16x32_bf16(kae1, qf[nt][1], ye, 0, 0, 0);
      yo = __builtin_amdgcn_mfma_f32_16x16x32_bf16(kao0, qf[nt][0], yo, 0, 0, 0);
      yo = __builtin_amdgcn_mfma_f32_16x16x32_bf16(kao1, qf[nt][1], yo, 0, 0, 0);
      __builtin_amdgcn_s_setprio(0);
      short8 pa8;
      pa8[0] = (short)f2bf(__builtin_amdgcn_exp2f(ye[0]) * s4e.x);
      pa8[1] = (short)f2bf(__builtin_amdgcn_exp2f(ye[1]) * s4e.y);
      pa8[2] = (short)f2bf(__builtin_amdgcn_exp2f(ye[2]) * s4e.z);
      pa8[3] = (short)f2bf(__builtin_amdgcn_exp2f(ye[3]) * s4e.w);
      pa8[4] = (short)f2bf(__builtin_amdgcn_exp2f(yo[0]) * s4o.x);
      pa8[5] = (short)f2bf(__builtin_amdgcn_exp2f(yo[1]) * s4o.y);
      pa8[6] = (short)f2bf(__builtin_amdgcn_exp2f(yo[2]) * s4o.z);
      pa8[7] = (short)f2bf(__builtin_amdgcn_exp2f(yo[3]) * s4o.w);
      __builtin_amdgcn_s_setprio(1);
#pragma unroll
      for (int et = 0; et < 4; ++et)
        oacc[nt][et] = __builtin_amdgcn_mfma_f32_16x16x32_bf16(pa8, vb8[et], oacc[nt][et], 0, 0, 0);
      __builtin_amdgcn_s_setprio(0);
    }
    kae0 = nkae0; kae1 = nkae1; kao0 = nkao0; kao1 = nkao1;
#pragma unroll
    for (int et = 0; et < 4; ++et) vb8[et] = nvb8[et];
    s4e = ns4e; s4o = ns4o;
  }

#pragma unroll
  for (int nt = 0; nt < 4; ++nt)
#pragma unroll
    for (int et = 0; et < 4; ++et)
#pragma unroll
      for (int r = 0; r < 4; ++r)
        red[(w * 64 + nt * 16 + quad * 4 + r) * 68 + et * 16 + l16] = oacc[nt][et][r];
  __syncthreads();
  float* og = out + ((size_t)b * LL + qbase + w * 16) * 512 + h * 64;
#pragma unroll
  for (int i = 0; i < 16; ++i) {
    int row = w * 16 + i;
    float s = red[(0 * 64 + row) * 68 + lane] + red[(1 * 64 + row) * 68 + lane] +
              red[(2 * 64 + row) * 68 + lane] + red[(3 * 64 + row) * 68 + lane];
    og[(size_t)i * 512 + lane] = s;
  }
}

// ==================== fused persistent cooperative kernel ====================
// 512 blocks x 256 thr = 2 blocks/CU (LDS 68KB). Block blk owns bh = blk&15 for
// proj/stats/attn -> QA/KA/VB/S for a bh are produced AND consumed on XCD blk%8's
// L2 (bh%8 == blk%8). grid.sync() between phases replaces 3 kernel drains.
__global__ __launch_bounds__(256, 2) void fused_kernel(
    const float* __restrict__ queries, const float* __restrict__ keys,
    const float* __restrict__ values, const float* __restrict__ WQ,
    const float* __restrict__ WK, const float* __restrict__ WV,
    u16* __restrict__ wsb, float* __restrict__ out) {
  __shared__ __align__(16) union {
    u16   Xs[16 * 520];        // prep:  16.6 KB
    float Cs[64 * 68];         // proj:  17.4 KB
    float Sred[4 * 64];        // stats:  1.0 KB
    float red[4 * 64 * 68];    // attn:  69.6 KB
  } sm;
  cg::grid_group grid = cg::this_grid();
  int t = threadIdx.x;
  int blk = blockIdx.x;
  int bh = blk & 15, QT = blk >> 4;            // QT doubles as KT in stats

  for (int vb = blk; vb < 1152; vb += 512)
    prep_body(vb, t, sm.Xs, queries, keys, values, WQ, WK, WV, wsb);
  __threadfence();
  grid.sync();

#pragma unroll 1
  for (int z = 0; z < 3; ++z)
    proj_body(z, bh, QT, t, sm.Cs, wsb);
  __threadfence();
  grid.sync();

  stats_body(bh, QT, t, sm.Sred, wsb);
  __threadfence();
  grid.sync();

  attn_body(bh, QT, t, sm.red, wsb, out);
}

// ==================== fallback 4-kernel path (identical math) ====================
__global__ __launch_bounds__(256) void prep_kernel(
    const float* __restrict__ queries, const float* __restrict__ keys,
    const float* __restrict__ values, const float* __restrict__ WQ,
    const float* __restrict__ WK, const float* __restrict__ WV,
    u16* __restrict__ wsb) {
  __shared__ __align__(16) u16 Xs[16 * 520];
  prep_body(blockIdx.x, threadIdx.x, Xs, queries, keys, values, WQ, WK, WV, wsb);
}
__global__ __launch_bounds__(256) void proj_kernel(u16* __restrict__ wsb) {
  __shared__ float Cs[64 * 68];
  proj_body(blockIdx.z, blockIdx.y, blockIdx.x, threadIdx.x, Cs, wsb);
}
__global__ __launch_bounds__(256) void stats_kernel(u16* __restrict__ wsb) {
  __shared__ float Sred[4 * 64];
  stats_body(blockIdx.x, blockIdx.y, threadIdx.x, Sred, wsb);
}
__global__ __launch_bounds__(256, 2) void attn_kernel(const u16* __restrict__ wsb,
                                                      float* __restrict__ out) {
  __shared__ float red[4 * 64 * 68];
  attn_body(blockIdx.x, blockIdx.y, threadIdx.x, red, wsb, out);
}

extern "C" void kernel_launch(void* const* d_in, const int* in_sizes, int n_in,
                              void* d_out, int out_size, void* d_ws, size_t ws_size,
                              hipStream_t stream) {
  const float* keys    = (const float*)d_in[0];
  const float* queries = (const float*)d_in[1];
  const float* values  = (const float*)d_in[2];
  const float* WQ      = (const float*)d_in[3];
  const float* WK      = (const float*)d_in[4];
  const float* WV      = (const float*)d_in[5];
  float* out = (float*)d_out;
  u16* wsb = (u16*)d_ws;

  void* args[] = {(void*)&queries, (void*)&keys, (void*)&values,
                  (void*)&WQ, (void*)&WK, (void*)&WV, (void*)&wsb, (void*)&out};
  hipError_t err = hipLaunchCooperativeKernel((const void*)fused_kernel,
                                              dim3(512), dim3(256), args, 0, stream);
  if (err != hipSuccess) {
    // fallback: proven 4-kernel path
    prep_kernel<<<dim3(1152), 256, 0, stream>>>(queries, keys, values, WQ, WK, WV, wsb);
    proj_kernel<<<dim3(32, 16, 3), 256, 0, stream>>>(wsb);
    stats_kernel<<<dim3(16, 32), 256, 0, stream>>>(wsb);
    attn_kernel<<<dim3(16, 32), 256, 0, stream>>>(wsb, out);
  }
}

// Round 7
// 137.331 us; speedup vs baseline: 3.4078x; 3.4078x over previous
//
#include <hip/hip_runtime.h>
#include <hip/hip_bf16.h>

#define LL 2048
#define DM 512
// (1/sqrt(2048)) * log2(e): softmax exp(x) computed as exp2(x'); fold into Q pre-scale
#define SCALE2 0.031879357f

typedef unsigned short u16;
typedef __attribute__((ext_vector_type(8))) short short8;    // 8 bf16 (4 VGPRs)
typedef __attribute__((ext_vector_type(4))) short short4v;   // 4 bf16 (2 VGPRs)
typedef __attribute__((ext_vector_type(4))) float f32x4;     // MFMA C/D

// ws layout (u16 element offsets), ~27 MB of the 256 MiB ws:
//  XAQ/XAK/XAV: bf16 inputs in proj-A-frag order [2][128 r16][16 kt][64 lane][8]
//  WB : bf16 weights in B-frag order [3][8][16 kt][4 nt][64 lane][8]
//  QA/KA: bf16 Q,K projections in frag order (Q pre-scaled by SCALE2)
//  VB : bf16 V in PAIRED PV-B-frag order [16 kt2][4 w][4 et][64 lane][8]
//       (j<4 = keys of kt=2*kt2, j>=4 = keys of kt=2*kt2+1) for K=32 PV MFMA
//  S  : f32 Sinv [16][2048] (written by stats, one block per (bh,KT))
#define XAQ_OFF 0u
#define XAK_OFF 2097152u
#define XAV_OFF 4194304u
#define WB_OFF  6291456u
#define QA_OFF  7077888u
#define KA_OFF  9175040u
#define VB_OFF  11272192u
#define S_OFF   13369344u    // float region, 32768 floats

__device__ __forceinline__ u16 f2bf(float f) {
  union { float f; unsigned u; } v; v.f = f;
  unsigned r = v.u + 0x7fff + ((v.u >> 16) & 1);   // RNE
  return (u16)(r >> 16);
}
__device__ __forceinline__ size_t frag_idx(int bh, int t64, int w, int c, int lane) {
  return ((((size_t)(bh * 32 + t64) * 4 + w) * 2 + c) * 64 + lane) * 8;
}
// paired VB layout for K=32 PV: 16B word per (kt2,w,et,lane)
__device__ __forceinline__ size_t vb8_idx(int bh, int kt2, int w, int et, int lane) {
  return ((((size_t)(bh * 16 + kt2) * 4 + w) * 4 + et) * 64 + lane) * 8;
}

// ---------------- prep: X -> frag order via LDS transpose; W -> B-frag order ----------------
__global__ __launch_bounds__(256) void prep_kernel(
    const float* __restrict__ queries, const float* __restrict__ keys,
    const float* __restrict__ values, const float* __restrict__ WQ,
    const float* __restrict__ WK, const float* __restrict__ WV,
    u16* __restrict__ wsb) {
  int t = threadIdx.x;
  int blk = blockIdx.x;
  if (blk < 768) {
    int tens = blk >> 8;                       // 0=Q,1=K,2=V
    int grp  = blk & 255;                      // b*128 + r16
    const float* src = (tens == 0 ? queries : tens == 1 ? keys : values) +
                       (size_t)grp * 16 * 512;
    __shared__ __align__(16) u16 Xs[16][520];
#pragma unroll
    for (int rep = 0; rep < 8; ++rep) {
      int f4 = t + rep * 256;                  // 0..2047
      int row = f4 >> 7, c4 = f4 & 127;
      float4 v = *(const float4*)(src + (size_t)row * 512 + c4 * 4);
      short4v o;
      o[0] = (short)f2bf(v.x); o[1] = (short)f2bf(v.y);
      o[2] = (short)f2bf(v.z); o[3] = (short)f2bf(v.w);
      *(short4v*)&Xs[row][c4 * 4] = o;
    }
    __syncthreads();
    u16* dst = wsb + (tens == 0 ? XAQ_OFF : tens == 1 ? XAK_OFF : XAV_OFF) +
               (size_t)grp * 16 * 64 * 8;
#pragma unroll
    for (int rep = 0; rep < 4; ++rep) {
      int o = t + rep * 256;                   // kt*64 + lane
      int kt = o >> 6, lane = o & 63;
      int quad = lane >> 4, l16 = lane & 15;
      short8 v = *(const short8*)&Xs[l16][kt * 32 + quad * 8];
      *(short8*)(dst + (size_t)o * 8) = v;
    }
  } else {
    int c2 = (blk - 768) * 256 + t;            // 0..98303
    int lane = c2 & 63;
    int nt = (c2 >> 6) & 3;
    int kt = (c2 >> 8) & 15;
    int h  = (c2 >> 12) & 7;
    int z  = c2 >> 15;
    int quad = lane >> 4, l16 = lane & 15;
    const float* W = (z == 0) ? WQ : (z == 1) ? WK : WV;
    const float* src = W + ((size_t)h * DM + kt * 32 + quad * 8) * 64 + nt * 16 + l16;
    short8 o;
#pragma unroll
    for (int j = 0; j < 8; ++j) o[j] = (short)f2bf(src[(size_t)j * 64]);
    *(short8*)(wsb + WB_OFF + (size_t)c2 * 8) = o;
  }
}

// ---------------- proj: barrier-free MFMA GEMM; coalesced frag-order epilogue via LDS ----------------
// XCD write-locality swizzle: (z,bh,QT) derived from the linear block id so that
// linear%8 == bh%8 -> QA/KA/VB of a bh are WRITTEN on the same XCD's L2 that
// stats/attn (grids (bh,·): linear%8 == bh%8) will READ them from.
__global__ __launch_bounds__(256) void proj_kernel(u16* __restrict__ wsb) {
  int t = threadIdx.x;
  int lane = t & 63, w = t >> 6, quad = lane >> 4, l16 = lane & 15;
  int lin = blockIdx.x + 32 * (blockIdx.y + 16 * blockIdx.z);  // 0..1535
  int bh = lin & 15, QT = (lin >> 4) & 31, z = lin >> 9;       // bijective remap
  int b = bh >> 3, h = bh & 7;

  const u16* Bw = wsb + WB_OFF + ((size_t)(z * 8 + h) * 16) * 4 * 64 * 8;
  const u16* Ab = wsb + (z == 0 ? XAQ_OFF : z == 1 ? XAK_OFF : XAV_OFF) +
      (((size_t)b * 128 + QT * 4 + w) * 16) * 64 * 8;

  f32x4 acc[4];
#pragma unroll
  for (int nt = 0; nt < 4; ++nt) acc[nt] = (f32x4){0.f, 0.f, 0.f, 0.f};

#pragma unroll 4
  for (int kt = 0; kt < 16; ++kt) {
    short8 a = *(const short8*)(Ab + ((size_t)kt * 64 + lane) * 8);
#pragma unroll
    for (int nt = 0; nt < 4; ++nt) {
      short8 bb = *(const short8*)(Bw + (((size_t)kt * 4 + nt) * 64 + lane) * 8);
      acc[nt] = __builtin_amdgcn_mfma_f32_16x16x32_bf16(a, bb, acc[nt], 0, 0, 0);
    }
  }

  __shared__ float Cs[64][68];
  float sc = (z == 0) ? SCALE2 : 1.0f;         // exp2-fold: SCALE * log2(e)
#pragma unroll
  for (int nt = 0; nt < 4; ++nt)
#pragma unroll
    for (int r = 0; r < 4; ++r)
      Cs[w * 16 + quad * 4 + r][nt * 16 + l16] = acc[nt][r] * sc;
  __syncthreads();

  if (z < 2) {
    u16* base = wsb + (z == 0 ? QA_OFF : KA_OFF);
#pragma unroll
    for (int c = 0; c < 2; ++c) {
      const float* srcr = &Cs[w * 16 + l16][c * 32 + quad * 8];
      short8 o;
#pragma unroll
      for (int j = 0; j < 8; ++j) o[j] = (short)f2bf(srcr[j]);
      *(short8*)(base + frag_idx(bh, QT, w, c, lane)) = o;
    }
  } else {
    // paired PV-B layout: this block (kt = QT) writes the 8-byte half-word
    // (QT&1 ? j4-7 : j0-3) of each 16B K=32 B-fragment at kt2 = QT>>1
#pragma unroll
    for (int et = 0; et < 4; ++et) {
      short4v o;
#pragma unroll
      for (int j = 0; j < 4; ++j)
        o[j] = (short)f2bf(Cs[w * 16 + quad * 4 + j][et * 16 + l16]);
      *(short4v*)(wsb + VB_OFF + vb8_idx(bh, QT >> 1, w, et, lane) + (QT & 1) * 4) = o;
    }
  }
}

// ---------------- stats: one block per (bh,KT); Sinv[k] = 1/sum_q exp2(K·Q^T) ----------------
// grid (x=bh, y=KT): linear%8 == bh%8 -> all blocks of a bh land on one XCD,
// so the 32x QA re-read hits that XCD's L2 (now also WRITTEN there by proj).
__global__ __launch_bounds__(256) void stats_kernel(u16* __restrict__ wsb) {
  int t = threadIdx.x;
  int lane = t & 63, w = t >> 6, quad = lane >> 4, l16 = lane & 15;
  int bh = blockIdx.x;
  int KT = blockIdx.y;

  short8 ka[4][2];
#pragma unroll
  for (int mt = 0; mt < 4; ++mt)
#pragma unroll
    for (int c = 0; c < 2; ++c)
      ka[mt][c] = *(const short8*)(wsb + KA_OFF + frag_idx(bh, KT, mt, c, lane));

  float rs[4][4];
#pragma unroll
  for (int mt = 0; mt < 4; ++mt)
#pragma unroll
    for (int r = 0; r < 4; ++r) rs[mt][r] = 0.f;

  // 1-deep prefetch of next qt's Q fragments (wrap on last iter; values unused)
  short8 qb0 = *(const short8*)(wsb + QA_OFF + frag_idx(bh, 0, w, 0, lane));
  short8 qb1 = *(const short8*)(wsb + QA_OFF + frag_idx(bh, 0, w, 1, lane));
  for (int qt = 0; qt < 32; ++qt) {
    int qn = (qt + 1) & 31;
    short8 nq0 = *(const short8*)(wsb + QA_OFF + frag_idx(bh, qn, w, 0, lane));
    short8 nq1 = *(const short8*)(wsb + QA_OFF + frag_idx(bh, qn, w, 1, lane));
#pragma unroll
    for (int mt = 0; mt < 4; ++mt) {
      f32x4 y = (f32x4){0.f, 0.f, 0.f, 0.f};
      __builtin_amdgcn_s_setprio(1);
      y = __builtin_amdgcn_mfma_f32_16x16x32_bf16(ka[mt][0], qb0, y, 0, 0, 0);
      y = __builtin_amdgcn_mfma_f32_16x16x32_bf16(ka[mt][1], qb1, y, 0, 0, 0);
      __builtin_amdgcn_s_setprio(0);
#pragma unroll
      for (int r = 0; r < 4; ++r) rs[mt][r] += __builtin_amdgcn_exp2f(y[r]);
    }
    qb0 = nq0; qb1 = nq1;
  }
#pragma unroll
  for (int mt = 0; mt < 4; ++mt)
#pragma unroll
    for (int r = 0; r < 4; ++r) {
      rs[mt][r] += __shfl_xor(rs[mt][r], 1);
      rs[mt][r] += __shfl_xor(rs[mt][r], 2);
      rs[mt][r] += __shfl_xor(rs[mt][r], 4);
      rs[mt][r] += __shfl_xor(rs[mt][r], 8);
    }

  __shared__ float Sred[4][64];
  if (l16 == 0) {
#pragma unroll
    for (int mt = 0; mt < 4; ++mt)
#pragma unroll
      for (int r = 0; r < 4; ++r)
        Sred[w][mt * 16 + quad * 4 + r] = rs[mt][r];
  }
  __syncthreads();
  if (t < 64) {
    float s = Sred[0][t] + Sred[1][t] + Sred[2][t] + Sred[3][t];
    float* S = (float*)(wsb + S_OFF);
    S[(size_t)bh * LL + KT * 64 + t] = 1.0f / s;
  }
}

// ---------------- attn: P = exp2(y)*Sinv[k] in registers; K=32 PV MFMA; direct out ----------------
// grid (x=bh, y=QT) for the same XCD-L2 locality on KA/VB re-reads.
__global__ __launch_bounds__(256, 2) void attn_kernel(const u16* __restrict__ wsb,
                                                      float* __restrict__ out) {
  int t = threadIdx.x;
  int lane = t & 63, w = t >> 6, quad = lane >> 4, l16 = lane & 15;
  int bh = blockIdx.x, b = bh >> 3, h = bh & 7;
  int QT = blockIdx.y, qbase = QT * 64;
  const float* S = (const float*)(wsb + S_OFF) + (size_t)bh * LL;

  short8 qf[4][2];
#pragma unroll
  for (int nt = 0; nt < 4; ++nt)
#pragma unroll
    for (int c = 0; c < 2; ++c)
      qf[nt][c] = *(const short8*)(wsb + QA_OFF + frag_idx(bh, QT, nt, c, lane));

  f32x4 oacc[4][4];
#pragma unroll
  for (int nt = 0; nt < 4; ++nt)
#pragma unroll
    for (int et = 0; et < 4; ++et) oacc[nt][et] = (f32x4){0.f, 0.f, 0.f, 0.f};

  // 1-deep prefetch of next kt2's K(even,odd)/V-paired fragments and Sinv
  short8 kae0 = *(const short8*)(wsb + KA_OFF + frag_idx(bh, 0, w, 0, lane));
  short8 kae1 = *(const short8*)(wsb + KA_OFF + frag_idx(bh, 0, w, 1, lane));
  short8 kao0 = *(const short8*)(wsb + KA_OFF + frag_idx(bh, 1, w, 0, lane));
  short8 kao1 = *(const short8*)(wsb + KA_OFF + frag_idx(bh, 1, w, 1, lane));
  short8 vb8[4];
#pragma unroll
  for (int et = 0; et < 4; ++et)
    vb8[et] = *(const short8*)(wsb + VB_OFF + vb8_idx(bh, 0, w, et, lane));
  float4 s4e = *(const float4*)(S + 0 * 64 + w * 16 + quad * 4);
  float4 s4o = *(const float4*)(S + 1 * 64 + w * 16 + quad * 4);

  for (int kt2 = 0; kt2 < 16; ++kt2) {
    int kne = (2 * kt2 + 2) & 31, kno = (2 * kt2 + 3) & 31;
    int k2n = (kt2 + 1) & 15;
    short8 nkae0 = *(const short8*)(wsb + KA_OFF + frag_idx(bh, kne, w, 0, lane));
    short8 nkae1 = *(const short8*)(wsb + KA_OFF + frag_idx(bh, kne, w, 1, lane));
    short8 nkao0 = *(const short8*)(wsb + KA_OFF + frag_idx(bh, kno, w, 0, lane));
    short8 nkao1 = *(const short8*)(wsb + KA_OFF + frag_idx(bh, kno, w, 1, lane));
    short8 nvb8[4];
#pragma unroll
    for (int et = 0; et < 4; ++et)
      nvb8[et] = *(const short8*)(wsb + VB_OFF + vb8_idx(bh, k2n, w, et, lane));
    float4 ns4e = *(const float4*)(S + kne * 64 + w * 16 + quad * 4);
    float4 ns4o = *(const float4*)(S + kno * 64 + w * 16 + quad * 4);

#pragma unroll
    for (int nt = 0; nt < 4; ++nt) {
      f32x4 ye = (f32x4){0.f, 0.f, 0.f, 0.f};
      f32x4 yo = (f32x4){0.f, 0.f, 0.f, 0.f};
      __builtin_amdgcn_s_setprio(1);
      ye = __builtin_amdgcn_mfma_f32_16x16x32_bf16(kae0, qf[nt][0], ye, 0, 0, 0);
      ye = __builtin_amdgcn_mfma_f32_16x16x32_bf16(kae1, qf[nt][1], ye, 0, 0, 0);
      yo = __builtin_amdgcn_mfma_f32_16x16x32_bf16(kao0, qf[nt][0], yo, 0, 0, 0);
      yo = __builtin_amdgcn_mfma_f32_16x16x32_bf16(kao1, qf[nt][1], yo, 0, 0, 0);
      __builtin_amdgcn_s_setprio(0);
      short8 pa8;
      pa8[0] = (short)f2bf(__builtin_amdgcn_exp2f(ye[0]) * s4e.x);
      pa8[1] = (short)f2bf(__builtin_amdgcn_exp2f(ye[1]) * s4e.y);
      pa8[2] = (short)f2bf(__builtin_amdgcn_exp2f(ye[2]) * s4e.z);
      pa8[3] = (short)f2bf(__builtin_amdgcn_exp2f(ye[3]) * s4e.w);
      pa8[4] = (short)f2bf(__builtin_amdgcn_exp2f(yo[0]) * s4o.x);
      pa8[5] = (short)f2bf(__builtin_amdgcn_exp2f(yo[1]) * s4o.y);
      pa8[6] = (short)f2bf(__builtin_amdgcn_exp2f(yo[2]) * s4o.z);
      pa8[7] = (short)f2bf(__builtin_amdgcn_exp2f(yo[3]) * s4o.w);
      __builtin_amdgcn_s_setprio(1);
#pragma unroll
      for (int et = 0; et < 4; ++et)
        oacc[nt][et] = __builtin_amdgcn_mfma_f32_16x16x32_bf16(pa8, vb8[et], oacc[nt][et], 0, 0, 0);
      __builtin_amdgcn_s_setprio(0);
    }
    kae0 = nkae0; kae1 = nkae1; kao0 = nkao0; kao1 = nkao1;
#pragma unroll
    for (int et = 0; et < 4; ++et) vb8[et] = nvb8[et];
    s4e = ns4e; s4o = ns4o;
  }

  __shared__ float red[4][64][68];
#pragma unroll
  for (int nt = 0; nt < 4; ++nt)
#pragma unroll
    for (int et = 0; et < 4; ++et)
#pragma unroll
      for (int r = 0; r < 4; ++r)
        red[w][nt * 16 + quad * 4 + r][et * 16 + l16] = oacc[nt][et][r];
  __syncthreads();
  float* og = out + ((size_t)b * LL + qbase + w * 16) * 512 + h * 64;
#pragma unroll
  for (int i = 0; i < 16; ++i) {
    float s = red[0][w * 16 + i][lane] + red[1][w * 16 + i][lane] +
              red[2][w * 16 + i][lane] + red[3][w * 16 + i][lane];
    og[(size_t)i * 512 + lane] = s;
  }
}

extern "C" void kernel_launch(void* const* d_in, const int* in_sizes, int n_in,
                              void* d_out, int out_size, void* d_ws, size_t ws_size,
                              hipStream_t stream) {
  const float* keys    = (const float*)d_in[0];
  const float* queries = (const float*)d_in[1];
  const float* values  = (const float*)d_in[2];
  const float* WQ      = (const float*)d_in[3];
  const float* WK      = (const float*)d_in[4];
  const float* WV      = (const float*)d_in[5];
  float* out = (float*)d_out;
  u16* wsb = (u16*)d_ws;

  prep_kernel<<<dim3(1152), 256, 0, stream>>>(queries, keys, values, WQ, WK, WV, wsb);
  proj_kernel<<<dim3(32, 16, 3), 256, 0, stream>>>(wsb);
  stats_kernel<<<dim3(16, 32), 256, 0, stream>>>(wsb);
  attn_kernel<<<dim3(16, 32), 256, 0, stream>>>(wsb, out);
}

// Round 8
// 135.234 us; speedup vs baseline: 3.4606x; 1.0155x over previous
//
#include <hip/hip_runtime.h>
#include <hip/hip_bf16.h>

#define LL 2048
#define DM 512
// (1/sqrt(2048)) * log2(e): softmax exp(x) computed as exp2(x'); fold into Q pre-scale
#define SCALE2 0.031879357f

typedef unsigned short u16;
typedef __attribute__((ext_vector_type(8))) short short8;    // 8 bf16 (4 VGPRs)
typedef __attribute__((ext_vector_type(4))) short short4v;   // 4 bf16 (2 VGPRs)
typedef __attribute__((ext_vector_type(4))) float f32x4;     // MFMA C/D

// ws layout (u16 element offsets), ~27 MB of the 256 MiB ws:
//  XAQ/XAK/XAV: bf16 inputs in proj-A-frag order [2][128 r16][16 kt][64 lane][8]
//  WB : bf16 weights in B-frag order [3][8][16 kt][4 nt][64 lane][8]
//  QA/KA: bf16 Q,K projections in frag order (Q pre-scaled by SCALE2)
//  VB : bf16 V in PAIRED PV-B-frag order [16 kt2][4 w][4 et][64 lane][8]
//       (j<4 = keys of kt=2*kt2, j>=4 = keys of kt=2*kt2+1) for K=32 PV MFMA
//  S  : f32 Sinv [16][2048] (written by stats, one block per (bh,KT))
#define XAQ_OFF 0u
#define XAK_OFF 2097152u
#define XAV_OFF 4194304u
#define WB_OFF  6291456u
#define QA_OFF  7077888u
#define KA_OFF  9175040u
#define VB_OFF  11272192u
#define S_OFF   13369344u    // float region, 32768 floats

__device__ __forceinline__ u16 f2bf(float f) {
  union { float f; unsigned u; } v; v.f = f;
  unsigned r = v.u + 0x7fff + ((v.u >> 16) & 1);   // RNE
  return (u16)(r >> 16);
}
__device__ __forceinline__ size_t frag_idx(int bh, int t64, int w, int c, int lane) {
  return ((((size_t)(bh * 32 + t64) * 4 + w) * 2 + c) * 64 + lane) * 8;
}
// paired VB layout for K=32 PV: 16B word per (kt2,w,et,lane)
__device__ __forceinline__ size_t vb8_idx(int bh, int kt2, int w, int et, int lane) {
  return ((((size_t)(bh * 16 + kt2) * 4 + w) * 4 + et) * 64 + lane) * 8;
}

// ---------------- prep: X -> frag order via LDS transpose; W -> B-frag order ----------------
__global__ __launch_bounds__(256) void prep_kernel(
    const float* __restrict__ queries, const float* __restrict__ keys,
    const float* __restrict__ values, const float* __restrict__ WQ,
    const float* __restrict__ WK, const float* __restrict__ WV,
    u16* __restrict__ wsb) {
  int t = threadIdx.x;
  int blk = blockIdx.x;
  if (blk < 768) {
    int tens = blk >> 8;                       // 0=Q,1=K,2=V
    int grp  = blk & 255;                      // b*128 + r16
    const float* src = (tens == 0 ? queries : tens == 1 ? keys : values) +
                       (size_t)grp * 16 * 512;
    __shared__ __align__(16) u16 Xs[16][520];
#pragma unroll
    for (int rep = 0; rep < 8; ++rep) {
      int f4 = t + rep * 256;                  // 0..2047
      int row = f4 >> 7, c4 = f4 & 127;
      float4 v = *(const float4*)(src + (size_t)row * 512 + c4 * 4);
      short4v o;
      o[0] = (short)f2bf(v.x); o[1] = (short)f2bf(v.y);
      o[2] = (short)f2bf(v.z); o[3] = (short)f2bf(v.w);
      *(short4v*)&Xs[row][c4 * 4] = o;
    }
    __syncthreads();
    u16* dst = wsb + (tens == 0 ? XAQ_OFF : tens == 1 ? XAK_OFF : XAV_OFF) +
               (size_t)grp * 16 * 64 * 8;
#pragma unroll
    for (int rep = 0; rep < 4; ++rep) {
      int o = t + rep * 256;                   // kt*64 + lane
      int kt = o >> 6, lane = o & 63;
      int quad = lane >> 4, l16 = lane & 15;
      short8 v = *(const short8*)&Xs[l16][kt * 32 + quad * 8];
      *(short8*)(dst + (size_t)o * 8) = v;
    }
  } else {
    int c2 = (blk - 768) * 256 + t;            // 0..98303
    int lane = c2 & 63;
    int nt = (c2 >> 6) & 3;
    int kt = (c2 >> 8) & 15;
    int h  = (c2 >> 12) & 7;
    int z  = c2 >> 15;
    int quad = lane >> 4, l16 = lane & 15;
    const float* W = (z == 0) ? WQ : (z == 1) ? WK : WV;
    const float* src = W + ((size_t)h * DM + kt * 32 + quad * 8) * 64 + nt * 16 + l16;
    short8 o;
#pragma unroll
    for (int j = 0; j < 8; ++j) o[j] = (short)f2bf(src[(size_t)j * 64]);
    *(short8*)(wsb + WB_OFF + (size_t)c2 * 8) = o;
  }
}

// ---------------- proj: barrier-free MFMA GEMM; coalesced frag-order epilogue via LDS ----------------
__global__ __launch_bounds__(256) void proj_kernel(u16* __restrict__ wsb) {
  int t = threadIdx.x;
  int lane = t & 63, w = t >> 6, quad = lane >> 4, l16 = lane & 15;
  int z = blockIdx.z, bh = blockIdx.y, b = bh >> 3, h = bh & 7;
  int QT = blockIdx.x;

  const u16* Bw = wsb + WB_OFF + ((size_t)(z * 8 + h) * 16) * 4 * 64 * 8;
  const u16* Ab = wsb + (z == 0 ? XAQ_OFF : z == 1 ? XAK_OFF : XAV_OFF) +
      (((size_t)b * 128 + QT * 4 + w) * 16) * 64 * 8;

  f32x4 acc[4];
#pragma unroll
  for (int nt = 0; nt < 4; ++nt) acc[nt] = (f32x4){0.f, 0.f, 0.f, 0.f};

#pragma unroll 4
  for (int kt = 0; kt < 16; ++kt) {
    short8 a = *(const short8*)(Ab + ((size_t)kt * 64 + lane) * 8);
#pragma unroll
    for (int nt = 0; nt < 4; ++nt) {
      short8 bb = *(const short8*)(Bw + (((size_t)kt * 4 + nt) * 64 + lane) * 8);
      acc[nt] = __builtin_amdgcn_mfma_f32_16x16x32_bf16(a, bb, acc[nt], 0, 0, 0);
    }
  }

  __shared__ float Cs[64][68];
  float sc = (z == 0) ? SCALE2 : 1.0f;         // exp2-fold: SCALE * log2(e)
#pragma unroll
  for (int nt = 0; nt < 4; ++nt)
#pragma unroll
    for (int r = 0; r < 4; ++r)
      Cs[w * 16 + quad * 4 + r][nt * 16 + l16] = acc[nt][r] * sc;
  __syncthreads();

  if (z < 2) {
    u16* base = wsb + (z == 0 ? QA_OFF : KA_OFF);
#pragma unroll
    for (int c = 0; c < 2; ++c) {
      const float* srcr = &Cs[w * 16 + l16][c * 32 + quad * 8];
      short8 o;
#pragma unroll
      for (int j = 0; j < 8; ++j) o[j] = (short)f2bf(srcr[j]);
      *(short8*)(base + frag_idx(bh, QT, w, c, lane)) = o;
    }
  } else {
    // paired PV-B layout: this block (kt = QT) writes the 8-byte half-word
    // (QT&1 ? j4-7 : j0-3) of each 16B K=32 B-fragment at kt2 = QT>>1
#pragma unroll
    for (int et = 0; et < 4; ++et) {
      short4v o;
#pragma unroll
      for (int j = 0; j < 4; ++j)
        o[j] = (short)f2bf(Cs[w * 16 + quad * 4 + j][et * 16 + l16]);
      *(short4v*)(wsb + VB_OFF + vb8_idx(bh, QT >> 1, w, et, lane) + (QT & 1) * 4) = o;
    }
  }
}

// ---------------- stats: one block per (bh,KT); Sinv[k] = 1/sum_q exp2(K·Q^T) ----------------
// 3-deep Q prefetch (3-set rotation, all indices static): every Q load has ~3
// iterations (~1500 cy) of slack to cover L3 latency (L2 is invalidated at the
// proj->stats kernel boundary, so all frag reads are L3 hits ~600-900 cy).
#define STATS_PHASE(QB0, QB1, QNEW)                                             \
  {                                                                             \
    _Pragma("unroll")                                                           \
    for (int mt = 0; mt < 4; ++mt) {                                            \
      f32x4 y = (f32x4){0.f, 0.f, 0.f, 0.f};                                    \
      __builtin_amdgcn_s_setprio(1);                                            \
      y = __builtin_amdgcn_mfma_f32_16x16x32_bf16(ka[mt][0], QB0, y, 0, 0, 0);  \
      y = __builtin_amdgcn_mfma_f32_16x16x32_bf16(ka[mt][1], QB1, y, 0, 0, 0);  \
      __builtin_amdgcn_s_setprio(0);                                            \
      _Pragma("unroll")                                                         \
      for (int r = 0; r < 4; ++r) rs[mt][r] += __builtin_amdgcn_exp2f(y[r]);    \
    }                                                                           \
    QB0 = *(const short8*)(wsb + QA_OFF + frag_idx(bh, (QNEW) & 31, w, 0, lane)); \
    QB1 = *(const short8*)(wsb + QA_OFF + frag_idx(bh, (QNEW) & 31, w, 1, lane)); \
  }

__global__ __launch_bounds__(256) void stats_kernel(u16* __restrict__ wsb) {
  int t = threadIdx.x;
  int lane = t & 63, w = t >> 6, quad = lane >> 4, l16 = lane & 15;
  int bh = blockIdx.x;
  int KT = blockIdx.y;

  short8 ka[4][2];
#pragma unroll
  for (int mt = 0; mt < 4; ++mt)
#pragma unroll
    for (int c = 0; c < 2; ++c)
      ka[mt][c] = *(const short8*)(wsb + KA_OFF + frag_idx(bh, KT, mt, c, lane));

  float rs[4][4];
#pragma unroll
  for (int mt = 0; mt < 4; ++mt)
#pragma unroll
    for (int r = 0; r < 4; ++r) rs[mt][r] = 0.f;

  // pre-issue 3 Q sets: A<-0, B<-1, C<-2
  short8 qA0 = *(const short8*)(wsb + QA_OFF + frag_idx(bh, 0, w, 0, lane));
  short8 qA1 = *(const short8*)(wsb + QA_OFF + frag_idx(bh, 0, w, 1, lane));
  short8 qB0 = *(const short8*)(wsb + QA_OFF + frag_idx(bh, 1, w, 0, lane));
  short8 qB1 = *(const short8*)(wsb + QA_OFF + frag_idx(bh, 1, w, 1, lane));
  short8 qC0 = *(const short8*)(wsb + QA_OFF + frag_idx(bh, 2, w, 0, lane));
  short8 qC1 = *(const short8*)(wsb + QA_OFF + frag_idx(bh, 2, w, 1, lane));

#pragma unroll 1
  for (int j = 0; j < 10; ++j) {               // computes qt = 0..29
    int k0 = 3 * j;
    STATS_PHASE(qA0, qA1, k0 + 3);             // compute 3j,   reissue A <- 3j+3
    STATS_PHASE(qB0, qB1, k0 + 4);             // compute 3j+1, reissue B <- 3j+4
    STATS_PHASE(qC0, qC1, k0 + 5);             // compute 3j+2, reissue C <- 3j+5
  }
  STATS_PHASE(qA0, qA1, 0);                    // qt = 30 (tail reloads are dead, DCE'd)
  STATS_PHASE(qB0, qB1, 0);                    // qt = 31

#pragma unroll
  for (int mt = 0; mt < 4; ++mt)
#pragma unroll
    for (int r = 0; r < 4; ++r) {
      rs[mt][r] += __shfl_xor(rs[mt][r], 1);
      rs[mt][r] += __shfl_xor(rs[mt][r], 2);
      rs[mt][r] += __shfl_xor(rs[mt][r], 4);
      rs[mt][r] += __shfl_xor(rs[mt][r], 8);
    }

  __shared__ float Sred[4][64];
  if (l16 == 0) {
#pragma unroll
    for (int mt = 0; mt < 4; ++mt)
#pragma unroll
      for (int r = 0; r < 4; ++r)
        Sred[w][mt * 16 + quad * 4 + r] = rs[mt][r];
  }
  __syncthreads();
  if (t < 64) {
    float s = Sred[0][t] + Sred[1][t] + Sred[2][t] + Sred[3][t];
    float* S = (float*)(wsb + S_OFF);
    S[(size_t)bh * LL + KT * 64 + t] = 1.0f / s;
  }
}

// ---------------- attn: P = exp2(y)*Sinv[k] in registers; K=32 PV MFMA; direct out ----------------
// 3-deep K/V/S prefetch via 3-set rotation (static indices, no register copies):
// each set's loads get ~3 iterations of slack to cover L3 latency.
#define ATTN_PHASE(KE0, KE1, KO0, KO1, VBX, S4E, S4O, KNEW)                         \
  {                                                                                 \
    _Pragma("unroll")                                                               \
    for (int nt = 0; nt < 4; ++nt) {                                                \
      f32x4 ye = (f32x4){0.f, 0.f, 0.f, 0.f};                                       \
      f32x4 yo = (f32x4){0.f, 0.f, 0.f, 0.f};                                       \
      __builtin_amdgcn_s_setprio(1);                                                \
      ye = __builtin_amdgcn_mfma_f32_16x16x32_bf16(KE0, qf[nt][0], ye, 0, 0, 0);    \
      ye = __builtin_amdgcn_mfma_f32_16x16x32_bf16(KE1, qf[nt][1], ye, 0, 0, 0);    \
      yo = __builtin_amdgcn_mfma_f32_16x16x32_bf16(KO0, qf[nt][0], yo, 0, 0, 0);    \
      yo = __builtin_amdgcn_mfma_f32_16x16x32_bf16(KO1, qf[nt][1], yo, 0, 0, 0);    \
      __builtin_amdgcn_s_setprio(0);                                                \
      short8 pa8;                                                                   \
      pa8[0] = (short)f2bf(__builtin_amdgcn_exp2f(ye[0]) * S4E.x);                  \
      pa8[1] = (short)f2bf(__builtin_amdgcn_exp2f(ye[1]) * S4E.y);                  \
      pa8[2] = (short)f2bf(__builtin_amdgcn_exp2f(ye[2]) * S4E.z);                  \
      pa8[3] = (short)f2bf(__builtin_amdgcn_exp2f(ye[3]) * S4E.w);                  \
      pa8[4] = (short)f2bf(__builtin_amdgcn_exp2f(yo[0]) * S4O.x);                  \
      pa8[5] = (short)f2bf(__builtin_amdgcn_exp2f(yo[1]) * S4O.y);                  \
      pa8[6] = (short)f2bf(__builtin_amdgcn_exp2f(yo[2]) * S4O.z);                  \
      pa8[7] = (short)f2bf(__builtin_amdgcn_exp2f(yo[3]) * S4O.w);                  \
      __builtin_amdgcn_s_setprio(1);                                                \
      _Pragma("unroll")                                                             \
      for (int et = 0; et < 4; ++et)                                                \
        oacc[nt][et] = __builtin_amdgcn_mfma_f32_16x16x32_bf16(pa8, VBX[et],        \
                                                               oacc[nt][et], 0, 0, 0); \
      __builtin_amdgcn_s_setprio(0);                                                \
    }                                                                               \
    {                                                                               \
      int ke = (2 * (KNEW)) & 31, ko = (2 * (KNEW) + 1) & 31, kv = (KNEW) & 15;     \
      KE0 = *(const short8*)(wsb + KA_OFF + frag_idx(bh, ke, w, 0, lane));          \
      KE1 = *(const short8*)(wsb + KA_OFF + frag_idx(bh, ke, w, 1, lane));          \
      KO0 = *(const short8*)(wsb + KA_OFF + frag_idx(bh, ko, w, 0, lane));          \
      KO1 = *(const short8*)(wsb + KA_OFF + frag_idx(bh, ko, w, 1, lane));          \
      _Pragma("unroll")                                                             \
      for (int et = 0; et < 4; ++et)                                                \
        VBX[et] = *(const short8*)(wsb + VB_OFF + vb8_idx(bh, kv, w, et, lane));    \
      S4E = *(const float4*)(S + ke * 64 + w * 16 + quad * 4);                      \
      S4O = *(const float4*)(S + ko * 64 + w * 16 + quad * 4);                      \
    }                                                                               \
  }

#define ATTN_LOADSET(KE0, KE1, KO0, KO1, VBX, S4E, S4O, KT2)                        \
  {                                                                                 \
    int ke = 2 * (KT2), ko = 2 * (KT2) + 1;                                         \
    KE0 = *(const short8*)(wsb + KA_OFF + frag_idx(bh, ke, w, 0, lane));            \
    KE1 = *(const short8*)(wsb + KA_OFF + frag_idx(bh, ke, w, 1, lane));            \
    KO0 = *(const short8*)(wsb + KA_OFF + frag_idx(bh, ko, w, 0, lane));            \
    KO1 = *(const short8*)(wsb + KA_OFF + frag_idx(bh, ko, w, 1, lane));            \
    _Pragma("unroll")                                                               \
    for (int et = 0; et < 4; ++et)                                                  \
      VBX[et] = *(const short8*)(wsb + VB_OFF + vb8_idx(bh, (KT2), w, et, lane));   \
    S4E = *(const float4*)(S + ke * 64 + w * 16 + quad * 4);                        \
    S4O = *(const float4*)(S + ko * 64 + w * 16 + quad * 4);                        \
  }

__global__ __launch_bounds__(256, 2) void attn_kernel(const u16* __restrict__ wsb,
                                                      float* __restrict__ out) {
  int t = threadIdx.x;
  int lane = t & 63, w = t >> 6, quad = lane >> 4, l16 = lane & 15;
  int bh = blockIdx.x, b = bh >> 3, h = bh & 7;
  int QT = blockIdx.y, qbase = QT * 64;
  const float* S = (const float*)(wsb + S_OFF) + (size_t)bh * LL;

  short8 qf[4][2];
#pragma unroll
  for (int nt = 0; nt < 4; ++nt)
#pragma unroll
    for (int c = 0; c < 2; ++c)
      qf[nt][c] = *(const short8*)(wsb + QA_OFF + frag_idx(bh, QT, nt, c, lane));

  f32x4 oacc[4][4];
#pragma unroll
  for (int nt = 0; nt < 4; ++nt)
#pragma unroll
    for (int et = 0; et < 4; ++et) oacc[nt][et] = (f32x4){0.f, 0.f, 0.f, 0.f};

  // 3 register sets (A,B,C), pre-issued for kt2 = 0,1,2
  short8 aKE0, aKE1, aKO0, aKO1, aVB[4]; float4 aSE, aSO;
  short8 bKE0, bKE1, bKO0, bKO1, bVB[4]; float4 bSE, bSO;
  short8 cKE0, cKE1, cKO0, cKO1, cVB[4]; float4 cSE, cSO;
  ATTN_LOADSET(aKE0, aKE1, aKO0, aKO1, aVB, aSE, aSO, 0)
  ATTN_LOADSET(bKE0, bKE1, bKO0, bKO1, bVB, bSE, bSO, 1)
  ATTN_LOADSET(cKE0, cKE1, cKO0, cKO1, cVB, cSE, cSO, 2)

#pragma unroll 1
  for (int j = 0; j < 5; ++j) {                // computes kt2 = 0..14
    int k0 = 3 * j;
    ATTN_PHASE(aKE0, aKE1, aKO0, aKO1, aVB, aSE, aSO, k0 + 3)
    ATTN_PHASE(bKE0, bKE1, bKO0, bKO1, bVB, bSE, bSO, k0 + 4)
    ATTN_PHASE(cKE0, cKE1, cKO0, cKO1, cVB, cSE, cSO, k0 + 5)
  }
  ATTN_PHASE(aKE0, aKE1, aKO0, aKO1, aVB, aSE, aSO, 0)   // kt2 = 15 (tail reloads DCE'd)

  __shared__ float red[4][64][68];
#pragma unroll
  for (int nt = 0; nt < 4; ++nt)
#pragma unroll
    for (int et = 0; et < 4; ++et)
#pragma unroll
      for (int r = 0; r < 4; ++r)
        red[w][nt * 16 + quad * 4 + r][et * 16 + l16] = oacc[nt][et][r];
  __syncthreads();
  float* og = out + ((size_t)b * LL + qbase + w * 16) * 512 + h * 64;
#pragma unroll
  for (int i = 0; i < 16; ++i) {
    float s = red[0][w * 16 + i][lane] + red[1][w * 16 + i][lane] +
              red[2][w * 16 + i][lane] + red[3][w * 16 + i][lane];
    og[(size_t)i * 512 + lane] = s;
  }
}

extern "C" void kernel_launch(void* const* d_in, const int* in_sizes, int n_in,
                              void* d_out, int out_size, void* d_ws, size_t ws_size,
                              hipStream_t stream) {
  const float* keys    = (const float*)d_in[0];
  const float* queries = (const float*)d_in[1];
  const float* values  = (const float*)d_in[2];
  const float* WQ      = (const float*)d_in[3];
  const float* WK      = (const float*)d_in[4];
  const float* WV      = (const float*)d_in[5];
  float* out = (float*)d_out;
  u16* wsb = (u16*)d_ws;

  prep_kernel<<<dim3(1152), 256, 0, stream>>>(queries, keys, values, WQ, WK, WV, wsb);
  proj_kernel<<<dim3(32, 16, 3), 256, 0, stream>>>(wsb);
  stats_kernel<<<dim3(16, 32), 256, 0, stream>>>(wsb);
  attn_kernel<<<dim3(16, 32), 256, 0, stream>>>(wsb, out);
}

// Round 10
// 134.772 us; speedup vs baseline: 3.4724x; 1.0034x over previous
//
#include <hip/hip_runtime.h>
#include <hip/hip_bf16.h>

#define LL 2048
#define DM 512
// (1/sqrt(2048)) * log2(e): softmax exp(x) computed as exp2(x'); fold into Q pre-scale
#define SCALE2 0.031879357f

typedef unsigned short u16;
typedef __attribute__((ext_vector_type(8))) short short8;    // 8 bf16 (4 VGPRs)
typedef __attribute__((ext_vector_type(4))) short short4v;   // 4 bf16 (2 VGPRs)
typedef __attribute__((ext_vector_type(4))) float f32x4;     // MFMA C/D

// ws layout (u16 element offsets), ~27 MB of the 256 MiB ws:
//  XAQ/XAK/XAV: bf16 inputs in proj-A-frag order [2][128 r16][16 kt][64 lane][8]
//  WB : bf16 weights in B-frag order [3][8][16 kt][4 nt][64 lane][8]
//  QA/KA: bf16 Q,K projections in frag order (Q pre-scaled by SCALE2)
//  VB : bf16 V in PAIRED PV-B-frag order [16 kt2][4 w][4 et][64 lane][8]
//       (j<4 = keys of kt=2*kt2, j>=4 = keys of kt=2*kt2+1) for K=32 PV MFMA
//  S  : f32 Sinv [16][2048] (written by stats, one block per (bh,KT))
#define XAQ_OFF 0u
#define XAK_OFF 2097152u
#define XAV_OFF 4194304u
#define WB_OFF  6291456u
#define QA_OFF  7077888u
#define KA_OFF  9175040u
#define VB_OFF  11272192u
#define S_OFF   13369344u    // float region, 32768 floats

// 2x f32 -> packed bf16 dword. Scalar __float2bfloat16 casts (RNE); the compiler
// fuses adjacent pairs into v_cvt_pk_bf16_f32 (guide m240: this beats hand-asm).
__device__ __forceinline__ unsigned pk2(float lo, float hi) {
  union { __hip_bfloat162 h2; unsigned u; } v;
  v.h2.x = __float2bfloat16(lo);
  v.h2.y = __float2bfloat16(hi);
  return v.u;
}
__device__ __forceinline__ size_t frag_idx(int bh, int t64, int w, int c, int lane) {
  return ((((size_t)(bh * 32 + t64) * 4 + w) * 2 + c) * 64 + lane) * 8;
}
// paired VB layout for K=32 PV: 16B word per (kt2,w,et,lane)
__device__ __forceinline__ size_t vb8_idx(int bh, int kt2, int w, int et, int lane) {
  return ((((size_t)(bh * 16 + kt2) * 4 + w) * 4 + et) * 64 + lane) * 8;
}

// ---------------- prep: X -> frag order via LDS transpose; W -> B-frag order ----------------
__global__ __launch_bounds__(256) void prep_kernel(
    const float* __restrict__ queries, const float* __restrict__ keys,
    const float* __restrict__ values, const float* __restrict__ WQ,
    const float* __restrict__ WK, const float* __restrict__ WV,
    u16* __restrict__ wsb) {
  int t = threadIdx.x;
  int blk = blockIdx.x;
  if (blk < 768) {
    int tens = blk >> 8;                       // 0=Q,1=K,2=V
    int grp  = blk & 255;                      // b*128 + r16
    const float* src = (tens == 0 ? queries : tens == 1 ? keys : values) +
                       (size_t)grp * 16 * 512;
    __shared__ __align__(16) u16 Xs[16][520];
#pragma unroll
    for (int rep = 0; rep < 8; ++rep) {
      int f4 = t + rep * 256;                  // 0..2047
      int row = f4 >> 7, c4 = f4 & 127;
      float4 v = *(const float4*)(src + (size_t)row * 512 + c4 * 4);
      union { unsigned u[2]; short4v s; } o;
      o.u[0] = pk2(v.x, v.y);
      o.u[1] = pk2(v.z, v.w);
      *(short4v*)&Xs[row][c4 * 4] = o.s;
    }
    __syncthreads();
    u16* dst = wsb + (tens == 0 ? XAQ_OFF : tens == 1 ? XAK_OFF : XAV_OFF) +
               (size_t)grp * 16 * 64 * 8;
#pragma unroll
    for (int rep = 0; rep < 4; ++rep) {
      int o = t + rep * 256;                   // kt*64 + lane
      int kt = o >> 6, lane = o & 63;
      int quad = lane >> 4, l16 = lane & 15;
      short8 v = *(const short8*)&Xs[l16][kt * 32 + quad * 8];
      *(short8*)(dst + (size_t)o * 8) = v;
    }
  } else {
    int c2 = (blk - 768) * 256 + t;            // 0..98303
    int lane = c2 & 63;
    int nt = (c2 >> 6) & 3;
    int kt = (c2 >> 8) & 15;
    int h  = (c2 >> 12) & 7;
    int z  = c2 >> 15;
    int quad = lane >> 4, l16 = lane & 15;
    const float* W = (z == 0) ? WQ : (z == 1) ? WK : WV;
    const float* src = W + ((size_t)h * DM + kt * 32 + quad * 8) * 64 + nt * 16 + l16;
    float f[8];
#pragma unroll
    for (int j = 0; j < 8; ++j) f[j] = src[(size_t)j * 64];
    union { unsigned u[4]; short8 s; } o;
#pragma unroll
    for (int j = 0; j < 4; ++j) o.u[j] = pk2(f[2 * j], f[2 * j + 1]);
    *(short8*)(wsb + WB_OFF + (size_t)c2 * 8) = o.s;
  }
}

// ---------------- proj: barrier-free MFMA GEMM; coalesced frag-order epilogue via LDS ----------------
__global__ __launch_bounds__(256) void proj_kernel(u16* __restrict__ wsb) {
  int t = threadIdx.x;
  int lane = t & 63, w = t >> 6, quad = lane >> 4, l16 = lane & 15;
  int z = blockIdx.z, bh = blockIdx.y, b = bh >> 3, h = bh & 7;
  int QT = blockIdx.x;

  const u16* Bw = wsb + WB_OFF + ((size_t)(z * 8 + h) * 16) * 4 * 64 * 8;
  const u16* Ab = wsb + (z == 0 ? XAQ_OFF : z == 1 ? XAK_OFF : XAV_OFF) +
      (((size_t)b * 128 + QT * 4 + w) * 16) * 64 * 8;

  f32x4 acc[4];
#pragma unroll
  for (int nt = 0; nt < 4; ++nt) acc[nt] = (f32x4){0.f, 0.f, 0.f, 0.f};

#pragma unroll 4
  for (int kt = 0; kt < 16; ++kt) {
    short8 a = *(const short8*)(Ab + ((size_t)kt * 64 + lane) * 8);
#pragma unroll
    for (int nt = 0; nt < 4; ++nt) {
      short8 bb = *(const short8*)(Bw + (((size_t)kt * 4 + nt) * 64 + lane) * 8);
      acc[nt] = __builtin_amdgcn_mfma_f32_16x16x32_bf16(a, bb, acc[nt], 0, 0, 0);
    }
  }

  __shared__ float Cs[64][68];
  float sc = (z == 0) ? SCALE2 : 1.0f;         // exp2-fold: SCALE * log2(e)
#pragma unroll
  for (int nt = 0; nt < 4; ++nt)
#pragma unroll
    for (int r = 0; r < 4; ++r)
      Cs[w * 16 + quad * 4 + r][nt * 16 + l16] = acc[nt][r] * sc;
  __syncthreads();

  if (z < 2) {
    u16* base = wsb + (z == 0 ? QA_OFF : KA_OFF);
#pragma unroll
    for (int c = 0; c < 2; ++c) {
      const float* srcr = &Cs[w * 16 + l16][c * 32 + quad * 8];
      union { unsigned u[4]; short8 s; } o;
#pragma unroll
      for (int j = 0; j < 4; ++j) o.u[j] = pk2(srcr[2 * j], srcr[2 * j + 1]);
      *(short8*)(base + frag_idx(bh, QT, w, c, lane)) = o.s;
    }
  } else {
    // paired PV-B layout: this block (kt = QT) writes the 8-byte half-word
    // (QT&1 ? j4-7 : j0-3) of each 16B K=32 B-fragment at kt2 = QT>>1
#pragma unroll
    for (int et = 0; et < 4; ++et) {
      union { unsigned u[2]; short4v s; } o;
      o.u[0] = pk2(Cs[w * 16 + quad * 4 + 0][et * 16 + l16],
                   Cs[w * 16 + quad * 4 + 1][et * 16 + l16]);
      o.u[1] = pk2(Cs[w * 16 + quad * 4 + 2][et * 16 + l16],
                   Cs[w * 16 + quad * 4 + 3][et * 16 + l16]);
      *(short4v*)(wsb + VB_OFF + vb8_idx(bh, QT >> 1, w, et, lane) + (QT & 1) * 4) = o.s;
    }
  }
}

// ---------------- stats: one block per (bh,KT); Sinv[k] = 1/sum_q exp2(K·Q^T) ----------------
// 3-deep Q prefetch (3-set rotation, all indices static).
#define STATS_PHASE(QB0, QB1, QNEW)                                             \
  {                                                                             \
    _Pragma("unroll")                                                           \
    for (int mt = 0; mt < 4; ++mt) {                                            \
      f32x4 y = (f32x4){0.f, 0.f, 0.f, 0.f};                                    \
      __builtin_amdgcn_s_setprio(1);                                            \
      y = __builtin_amdgcn_mfma_f32_16x16x32_bf16(ka[mt][0], QB0, y, 0, 0, 0);  \
      y = __builtin_amdgcn_mfma_f32_16x16x32_bf16(ka[mt][1], QB1, y, 0, 0, 0);  \
      __builtin_amdgcn_s_setprio(0);                                            \
      _Pragma("unroll")                                                         \
      for (int r = 0; r < 4; ++r) rs[mt][r] += __builtin_amdgcn_exp2f(y[r]);    \
    }                                                                           \
    QB0 = *(const short8*)(wsb + QA_OFF + frag_idx(bh, (QNEW) & 31, w, 0, lane)); \
    QB1 = *(const short8*)(wsb + QA_OFF + frag_idx(bh, (QNEW) & 31, w, 1, lane)); \
  }

__global__ __launch_bounds__(256) void stats_kernel(u16* __restrict__ wsb) {
  int t = threadIdx.x;
  int lane = t & 63, w = t >> 6, quad = lane >> 4, l16 = lane & 15;
  int bh = blockIdx.x;
  int KT = blockIdx.y;

  short8 ka[4][2];
#pragma unroll
  for (int mt = 0; mt < 4; ++mt)
#pragma unroll
    for (int c = 0; c < 2; ++c)
      ka[mt][c] = *(const short8*)(wsb + KA_OFF + frag_idx(bh, KT, mt, c, lane));

  float rs[4][4];
#pragma unroll
  for (int mt = 0; mt < 4; ++mt)
#pragma unroll
    for (int r = 0; r < 4; ++r) rs[mt][r] = 0.f;

  // pre-issue 3 Q sets: A<-0, B<-1, C<-2
  short8 qA0 = *(const short8*)(wsb + QA_OFF + frag_idx(bh, 0, w, 0, lane));
  short8 qA1 = *(const short8*)(wsb + QA_OFF + frag_idx(bh, 0, w, 1, lane));
  short8 qB0 = *(const short8*)(wsb + QA_OFF + frag_idx(bh, 1, w, 0, lane));
  short8 qB1 = *(const short8*)(wsb + QA_OFF + frag_idx(bh, 1, w, 1, lane));
  short8 qC0 = *(const short8*)(wsb + QA_OFF + frag_idx(bh, 2, w, 0, lane));
  short8 qC1 = *(const short8*)(wsb + QA_OFF + frag_idx(bh, 2, w, 1, lane));

#pragma unroll 1
  for (int j = 0; j < 10; ++j) {               // computes qt = 0..29
    int k0 = 3 * j;
    STATS_PHASE(qA0, qA1, k0 + 3);             // compute 3j,   reissue A <- 3j+3
    STATS_PHASE(qB0, qB1, k0 + 4);             // compute 3j+1, reissue B <- 3j+4
    STATS_PHASE(qC0, qC1, k0 + 5);             // compute 3j+2, reissue C <- 3j+5
  }
  STATS_PHASE(qA0, qA1, 0);                    // qt = 30 (tail reloads are dead)
  STATS_PHASE(qB0, qB1, 0);                    // qt = 31

#pragma unroll
  for (int mt = 0; mt < 4; ++mt)
#pragma unroll
    for (int r = 0; r < 4; ++r) {
      rs[mt][r] += __shfl_xor(rs[mt][r], 1);
      rs[mt][r] += __shfl_xor(rs[mt][r], 2);
      rs[mt][r] += __shfl_xor(rs[mt][r], 4);
      rs[mt][r] += __shfl_xor(rs[mt][r], 8);
    }

  __shared__ float Sred[4][64];
  if (l16 == 0) {
#pragma unroll
    for (int mt = 0; mt < 4; ++mt)
#pragma unroll
      for (int r = 0; r < 4; ++r)
        Sred[w][mt * 16 + quad * 4 + r] = rs[mt][r];
  }
  __syncthreads();
  if (t < 64) {
    float s = Sred[0][t] + Sred[1][t] + Sred[2][t] + Sred[3][t];
    float* S = (float*)(wsb + S_OFF);
    S[(size_t)bh * LL + KT * 64 + t] = 1.0f / s;
  }
}

// ---------------- attn: P = exp2(y)*Sinv[k] in registers; K=32 PV MFMA; direct out ----------------
// 3-deep K/V/S prefetch via 3-set rotation; P pack via pk2 (compiler-fused cvt_pk).
#define ATTN_PHASE(KE0, KE1, KO0, KO1, VBX, S4E, S4O, KNEW)                         \
  {                                                                                 \
    _Pragma("unroll")                                                               \
    for (int nt = 0; nt < 4; ++nt) {                                                \
      f32x4 ye = (f32x4){0.f, 0.f, 0.f, 0.f};                                       \
      f32x4 yo = (f32x4){0.f, 0.f, 0.f, 0.f};                                       \
      __builtin_amdgcn_s_setprio(1);                                                \
      ye = __builtin_amdgcn_mfma_f32_16x16x32_bf16(KE0, qf[nt][0], ye, 0, 0, 0);    \
      ye = __builtin_amdgcn_mfma_f32_16x16x32_bf16(KE1, qf[nt][1], ye, 0, 0, 0);    \
      yo = __builtin_amdgcn_mfma_f32_16x16x32_bf16(KO0, qf[nt][0], yo, 0, 0, 0);    \
      yo = __builtin_amdgcn_mfma_f32_16x16x32_bf16(KO1, qf[nt][1], yo, 0, 0, 0);    \
      __builtin_amdgcn_s_setprio(0);                                                \
      union { unsigned u[4]; short8 s; } pc;                                        \
      pc.u[0] = pk2(__builtin_amdgcn_exp2f(ye[0]) * S4E.x,                          \
                    __builtin_amdgcn_exp2f(ye[1]) * S4E.y);                         \
      pc.u[1] = pk2(__builtin_amdgcn_exp2f(ye[2]) * S4E.z,                          \
                    __builtin_amdgcn_exp2f(ye[3]) * S4E.w);                         \
      pc.u[2] = pk2(__builtin_amdgcn_exp2f(yo[0]) * S4O.x,                          \
                    __builtin_amdgcn_exp2f(yo[1]) * S4O.y);                         \
      pc.u[3] = pk2(__builtin_amdgcn_exp2f(yo[2]) * S4O.z,                          \
                    __builtin_amdgcn_exp2f(yo[3]) * S4O.w);                         \
      short8 pa8 = pc.s;                                                            \
      __builtin_amdgcn_s_setprio(1);                                                \
      _Pragma("unroll")                                                             \
      for (int et = 0; et < 4; ++et)                                                \
        oacc[nt][et] = __builtin_amdgcn_mfma_f32_16x16x32_bf16(pa8, VBX[et],        \
                                                               oacc[nt][et], 0, 0, 0); \
      __builtin_amdgcn_s_setprio(0);                                                \
    }                                                                               \
    {                                                                               \
      int ke = (2 * (KNEW)) & 31, ko = (2 * (KNEW) + 1) & 31, kv = (KNEW) & 15;     \
      KE0 = *(const short8*)(wsb + KA_OFF + frag_idx(bh, ke, w, 0, lane));          \
      KE1 = *(const short8*)(wsb + KA_OFF + frag_idx(bh, ke, w, 1, lane));          \
      KO0 = *(const short8*)(wsb + KA_OFF + frag_idx(bh, ko, w, 0, lane));          \
      KO1 = *(const short8*)(wsb + KA_OFF + frag_idx(bh, ko, w, 1, lane));          \
      _Pragma("unroll")                                                             \
      for (int et = 0; et < 4; ++et)                                                \
        VBX[et] = *(const short8*)(wsb + VB_OFF + vb8_idx(bh, kv, w, et, lane));    \
      S4E = *(const float4*)(S + ke * 64 + w * 16 + quad * 4);                      \
      S4O = *(const float4*)(S + ko * 64 + w * 16 + quad * 4);                      \
    }                                                                               \
  }

#define ATTN_LOADSET(KE0, KE1, KO0, KO1, VBX, S4E, S4O, KT2)                        \
  {                                                                                 \
    int ke = 2 * (KT2), ko = 2 * (KT2) + 1;                                         \
    KE0 = *(const short8*)(wsb + KA_OFF + frag_idx(bh, ke, w, 0, lane));            \
    KE1 = *(const short8*)(wsb + KA_OFF + frag_idx(bh, ke, w, 1, lane));            \
    KO0 = *(const short8*)(wsb + KA_OFF + frag_idx(bh, ko, w, 0, lane));            \
    KO1 = *(const short8*)(wsb + KA_OFF + frag_idx(bh, ko, w, 1, lane));            \
    _Pragma("unroll")                                                               \
    for (int et = 0; et < 4; ++et)                                                  \
      VBX[et] = *(const short8*)(wsb + VB_OFF + vb8_idx(bh, (KT2), w, et, lane));   \
    S4E = *(const float4*)(S + ke * 64 + w * 16 + quad * 4);                        \
    S4O = *(const float4*)(S + ko * 64 + w * 16 + quad * 4);                        \
  }

__global__ __launch_bounds__(256, 2) void attn_kernel(const u16* __restrict__ wsb,
                                                      float* __restrict__ out) {
  int t = threadIdx.x;
  int lane = t & 63, w = t >> 6, quad = lane >> 4, l16 = lane & 15;
  int bh = blockIdx.x, b = bh >> 3, h = bh & 7;
  int QT = blockIdx.y, qbase = QT * 64;
  const float* S = (const float*)(wsb + S_OFF) + (size_t)bh * LL;

  short8 qf[4][2];
#pragma unroll
  for (int nt = 0; nt < 4; ++nt)
#pragma unroll
    for (int c = 0; c < 2; ++c)
      qf[nt][c] = *(const short8*)(wsb + QA_OFF + frag_idx(bh, QT, nt, c, lane));

  f32x4 oacc[4][4];
#pragma unroll
  for (int nt = 0; nt < 4; ++nt)
#pragma unroll
    for (int et = 0; et < 4; ++et) oacc[nt][et] = (f32x4){0.f, 0.f, 0.f, 0.f};

  // 3 register sets (A,B,C), pre-issued for kt2 = 0,1,2
  short8 aKE0, aKE1, aKO0, aKO1, aVB[4]; float4 aSE, aSO;
  short8 bKE0, bKE1, bKO0, bKO1, bVB[4]; float4 bSE, bSO;
  short8 cKE0, cKE1, cKO0, cKO1, cVB[4]; float4 cSE, cSO;
  ATTN_LOADSET(aKE0, aKE1, aKO0, aKO1, aVB, aSE, aSO, 0)
  ATTN_LOADSET(bKE0, bKE1, bKO0, bKO1, bVB, bSE, bSO, 1)
  ATTN_LOADSET(cKE0, cKE1, cKO0, cKO1, cVB, cSE, cSO, 2)

#pragma unroll 1
  for (int j = 0; j < 5; ++j) {                // computes kt2 = 0..14
    int k0 = 3 * j;
    ATTN_PHASE(aKE0, aKE1, aKO0, aKO1, aVB, aSE, aSO, k0 + 3)
    ATTN_PHASE(bKE0, bKE1, bKO0, bKO1, bVB, bSE, bSO, k0 + 4)
    ATTN_PHASE(cKE0, cKE1, cKO0, cKO1, cVB, cSE, cSO, k0 + 5)
  }
  ATTN_PHASE(aKE0, aKE1, aKO0, aKO1, aVB, aSE, aSO, 0)   // kt2 = 15 (tail reloads dead)

  __shared__ float red[4][64][68];
#pragma unroll
  for (int nt = 0; nt < 4; ++nt)
#pragma unroll
    for (int et = 0; et < 4; ++et)
#pragma unroll
      for (int r = 0; r < 4; ++r)
        red[w][nt * 16 + quad * 4 + r][et * 16 + l16] = oacc[nt][et][r];
  __syncthreads();
  float* og = out + ((size_t)b * LL + qbase + w * 16) * 512 + h * 64;
#pragma unroll
  for (int i = 0; i < 16; ++i) {
    float s = red[0][w * 16 + i][lane] + red[1][w * 16 + i][lane] +
              red[2][w * 16 + i][lane] + red[3][w * 16 + i][lane];
    og[(size_t)i * 512 + lane] = s;
  }
}

extern "C" void kernel_launch(void* const* d_in, const int* in_sizes, int n_in,
                              void* d_out, int out_size, void* d_ws, size_t ws_size,
                              hipStream_t stream) {
  const float* keys    = (const float*)d_in[0];
  const float* queries = (const float*)d_in[1];
  const float* values  = (const float*)d_in[2];
  const float* WQ      = (const float*)d_in[3];
  const float* WK      = (const float*)d_in[4];
  const float* WV      = (const float*)d_in[5];
  float* out = (float*)d_out;
  u16* wsb = (u16*)d_ws;

  prep_kernel<<<dim3(1152), 256, 0, stream>>>(queries, keys, values, WQ, WK, WV, wsb);
  proj_kernel<<<dim3(32, 16, 3), 256, 0, stream>>>(wsb);
  stats_kernel<<<dim3(16, 32), 256, 0, stream>>>(wsb);
  attn_kernel<<<dim3(16, 32), 256, 0, stream>>>(wsb, out);
}